// Round 8
// baseline (127.872 us; speedup 1.0000x reference)
//
#include <hip/hip_runtime.h>

#define B_    512
#define IN_   256
#define H_    512
#define OUT_  64
#define NDEATH (B_ - 1)
#define NSORT  512          // NDEATH padded to pow2 for bitonic sort / bsearch
#define RTOL_ 1e-6
#define ATOL_ 1e-8
#define NTHR  512           // 8 waves/block -> 2 waves/SIMD
#define KT    32            // K-tile (per wavegroup), split-K x2

typedef __attribute__((ext_vector_type(4))) double d4_t;

// ---------------------------------------------------------------------------
// LDS-only barrier (R15): lgkmcnt(0)+s_barrier. Global prefetches ride across;
// the K-loop's only cross-wave dependency is LDS staging.
// ---------------------------------------------------------------------------
__device__ __forceinline__ void lbar() {
    asm volatile("s_waitcnt lgkmcnt(0)" ::: "memory");
    __builtin_amdgcn_s_barrier();
    asm volatile("" ::: "memory");
}

// ---------------------------------------------------------------------------
// per-block: bitonic-sort deaths into LDS, emit sorted tolerance windows.
// 512 threads (1 elem/thread fill, 256 comparators/round).
// ---------------------------------------------------------------------------
__device__ void sort_windows(const float* __restrict__ deaths,
                             double* sd, double* slo, double* shi, int t) {
    if (t < NSORT) sd[t] = (t < NDEATH) ? (double)deaths[t] : 1e300;
    __syncthreads();
    for (int k = 2; k <= NSORT; k <<= 1) {
        for (int j = k >> 1; j > 0; j >>= 1) {
            if (t < 256) {
                int l = ((t & ~(j - 1)) << 1) | (t & (j - 1));   // pair (l, l+j)
                int p = l + j;
                bool up = ((l & k) == 0);
                double a = sd[l], b = sd[p];
                if ((a > b) == up) { sd[l] = b; sd[p] = a; }
            }
            __syncthreads();
        }
    }
    if (t < NSORT) {
        double d = sd[t];
        double w = ATOL_ + RTOL_ * fabs(d);
        slo[t] = d - w;
        shi[t] = d + w;
    }
    __syncthreads();
}

// ---------------------------------------------------------------------------
// f64 MFMA GEMM phase (R16/R20 structure, byte-identical math): split-K x2
// across wavegroups; A staged via LDS (depth-3 register prefetch); B direct
// global->reg; two accumulators; one lgkm-only barrier per K-tile;
// s_setprio(1) around the MFMA cluster. R21: plain cached stores for C
// (kernel-boundary semantics replace the ast/L3 protocol).
// ---------------------------------------------------------------------------
template <typename TIN, bool RELU, int N, int K>
__device__ void gemm_dev(const TIN* __restrict__ A, const float* __restrict__ W,
                         const float* __restrict__ bias, double* __restrict__ C,
                         int tile, int t,
                         double (&As)[2][2][KT][33]) {
    const int lane  = t & 63;
    const int wave4 = (t >> 6) & 3;     // quarter selector (same for both wg)
    const int w2    = t >> 8;           // wavegroup = K-half
    const int tg    = t & 255;          // 256-thread-local id for staging map
    const int wm    = wave4 & 1, wn = wave4 >> 1;
    constexpr int nbx = N >> 5;
    const int row0  = (tile / nbx) << 5;
    const int col0  = (tile % nbx) << 5;

    const int akk   = tg & 31;          // k within A tile
    const int amm   = tg >> 5;          // base row (rows amm+8p, p=0..3)
    const int kbase = w2 * (K >> 1);
    constexpr int nkt = K >> 6;         // K-tiles per wavegroup

    const int mrow  = wm * 16 + (lane & 15);
    const int ncol  = wn * 16 + (lane & 15);
    const int kq    = lane >> 4;

    TIN   ar[3][4];
    float br[3][8];

    auto load_a = [&](int rs, int kt) {
        const int k0 = kbase + (kt << 5);
        #pragma unroll
        for (int p = 0; p < 4; ++p)
            ar[rs][p] = A[(size_t)(row0 + amm + 8 * p) * K + k0 + akk];
    };
    auto load_b = [&](int rs, int kt) {
        const int k0 = kbase + (kt << 5);
        const float* wp = W + (size_t)(k0 + kq) * N + col0 + ncol;
        #pragma unroll
        for (int ks = 0; ks < 8; ++ks)
            br[rs][ks] = wp[(size_t)(4 * ks) * N];
    };
    auto stage_a = [&](int rs, int buf) {
        #pragma unroll
        for (int p = 0; p < 4; ++p)
            As[w2][buf][akk][amm + 8 * p] = (double)ar[rs][p];
    };

    load_a(0, 0); load_b(0, 0);
    if (nkt > 1) { load_a(1, 1); load_b(1, 1); }
    if (nkt > 2) { load_a(2, 2); load_b(2, 2); }
    stage_a(0, 0);
    lbar();

    d4_t c4a = {0.0, 0.0, 0.0, 0.0};
    d4_t c4b = {0.0, 0.0, 0.0, 0.0};

    #pragma unroll
    for (int kt = 0; kt < nkt; ++kt) {
        const int cur = kt & 1;
        const int rs  = kt % 3;
        __builtin_amdgcn_s_setprio(1);
        #pragma unroll
        for (int ks = 0; ks < 4; ++ks) {
            double av = As[w2][cur][ks * 4 + kq][mrow];
            c4a = __builtin_amdgcn_mfma_f64_16x16x4f64(av, (double)br[rs][ks],
                                                       c4a, 0, 0, 0);
        }
        #pragma unroll
        for (int ks = 4; ks < 8; ++ks) {
            double av = As[w2][cur][ks * 4 + kq][mrow];
            c4b = __builtin_amdgcn_mfma_f64_16x16x4f64(av, (double)br[rs][ks],
                                                       c4b, 0, 0, 0);
        }
        __builtin_amdgcn_s_setprio(0);
        // slot rs fully consumed -> refill for kt+3
        if (kt + 3 < nkt) { load_a(rs, kt + 3); load_b(rs, kt + 3); }
        if (kt + 1 < nkt) stage_a((kt + 1) % 3, cur ^ 1); // disjoint buffer
        lbar();                                           // lgkm-only
    }

    d4_t c4 = c4a + c4b;

    // combine K-half partials: kw1 publishes, kw0 adds + epilogue.
    // cEx aliases As (all K-loop reads fenced by the final loop barrier).
    double (*cEx)[16][17] = (double (*)[16][17])(&As[0][0][0][0]);
    const int r4 = (lane >> 4) * 4;
    if (w2 == 1) {
        #pragma unroll
        for (int r = 0; r < 4; ++r)
            cEx[wave4][r4 + r][lane & 15] = c4[r];
    }
    lbar();
    if (w2 == 0) {
        #pragma unroll
        for (int r = 0; r < 4; ++r) {
            int row = row0 + wm * 16 + r4 + r;
            int col = col0 + wn * 16 + (lane & 15);
            double v = c4[r] + cEx[wave4][r4 + r][lane & 15] + (double)bias[col];
            if (RELU) v = v > 0.0 ? v : 0.0;
            C[(size_t)row * N + col] = v;
        }
    }
}

// XCD-local tile mapping (R19): blocks with equal bid&7 share an XCD ->
// a 16-block "group" g reads one 32-row A-strip from the same L2.
__device__ __forceinline__ int tile_map(int bid) {
    const int g = (bid & 7) | ((bid >> 7) << 3);
    const int c = (bid >> 3) & 15;
    return g * 16 + c;
}

// ---------------------------------------------------------------------------
// dispatch 1: GEMM1 (256 tiles) + sort block (bid==256) publishing windows.
// ---------------------------------------------------------------------------
__global__ __launch_bounds__(NTHR) void g1s_k(
    const float* __restrict__ batch, const float* __restrict__ W1,
    const float* __restrict__ b1, double* __restrict__ hA,
    const float* __restrict__ deaths, double* __restrict__ wbc) {
    __shared__ double As[2][2][KT][33];
    const int t = threadIdx.x, bid = blockIdx.x;
    if (bid == 256) {
        double* sd  = &As[0][0][0][0];        // 512 dbl
        double* slo = sd + NSORT;             // 512 dbl
        double* shi = sd + 2 * NSORT;         // 512 dbl (3*512 <= 4224)
        sort_windows(deaths, sd, slo, shi, t);
        if (t < NSORT) {
            wbc[t]         = slo[t];
            wbc[NSORT + t] = shi[t];
        }
        return;
    }
    gemm_dev<float, true, H_, IN_>(batch, W1, b1, hA, tile_map(bid), t, As);
}

// dispatches 2,3: full 512x512 GEMMs
template <bool RELU>
__global__ __launch_bounds__(NTHR) void gemm_k(
    const double* __restrict__ A, const float* __restrict__ W,
    const float* __restrict__ bias, double* __restrict__ C) {
    __shared__ double As[2][2][KT][33];
    gemm_dev<double, RELU, H_, H_>(A, W, bias, C, tile_map(blockIdx.x),
                                   threadIdx.x, As);
}

// dispatch 4: Wout GEMM, 32 tiles (512x64 output)
__global__ __launch_bounds__(NTHR) void gout_k(
    const double* __restrict__ hC, const float* __restrict__ Wout,
    const float* __restrict__ bout, double* __restrict__ yv) {
    __shared__ double As[2][2][KT][33];
    gemm_dev<double, false, OUT_, H_>(hC, Wout, bout, yv, blockIdx.x,
                                      threadIdx.x, As);
}

// ---------------------------------------------------------------------------
// pdist + sorted-window match. Block b: rows b and 510-b (512 pairs, balanced).
// ---------------------------------------------------------------------------
__device__ __forceinline__ double pair_val(const double* __restrict__ yrow_s,
                                           const double* __restrict__ yj,
                                           const double* __restrict__ slo,
                                           const double* __restrict__ shi) {
    double s = 0.0;
    #pragma unroll
    for (int d = 0; d < OUT_; d += 2) {
        double2 v = *(const double2*)(yj + d);
        double d0 = yrow_s[d]     - v.x;
        double d1 = yrow_s[d + 1] - v.y;
        s = fma(d0, d0, s);
        s = fma(d1, d1, s);
    }
    double pd = sqrt(s);
    int pos = 0;
    #pragma unroll
    for (int step = NSORT / 2; step; step >>= 1) {
        if (slo[pos + step - 1] <= pd) pos += step;
    }
    bool m = (pos > 0) && (shi[pos - 1] >= pd);
    return m ? pd : 0.0;
}

__device__ void pdist_dev(const double* __restrict__ y,
                          double* __restrict__ hom_part, int bid, int t,
                          double* yA, double* yB,
                          const double* slo, const double* shi) {
    const int iA = bid;
    const int iB = 510 - bid;     // == iA when bid == 255
    if (t < OUT_)            yA[t]        = y[(size_t)iA * OUT_ + t];
    else if (t < 2 * OUT_)   yB[t - OUT_] = y[(size_t)iB * OUT_ + (t - OUT_)];
    __syncthreads();

    double local = 0.0;
    for (int j = iA + 1 + t; j < B_; j += NTHR)
        local += pair_val(yA, y + (size_t)j * OUT_, slo, shi);
    if (iB != iA)
        for (int j = iB + 1 + t; j < B_; j += NTHR)
            local += pair_val(yB, y + (size_t)j * OUT_, slo, shi);

    for (int off = 32; off; off >>= 1) local += __shfl_down(local, off);
    __shared__ double sw[8];
    int wave = t >> 6, lane = t & 63;
    if (lane == 0) sw[wave] = local;
    __syncthreads();
    if (t == 0) {
        double s = 0.0;
        #pragma unroll
        for (int w = 0; w < 8; ++w) s += sw[w];
        hom_part[bid] = s;
    }
}

// ---------------------------------------------------------------------------
// column c: mean + target-MSE partial + compactness partial -> global slots
// ---------------------------------------------------------------------------
__device__ void mc_dev(const float* __restrict__ target,
                       const double* __restrict__ y,
                       double* __restrict__ t_part, double* __restrict__ c_part,
                       int c, int t) {
    const int wave = t >> 6, lane = t & 63;
    double v = y[(size_t)t * OUT_ + c];
    double s = v;
    for (int off = 32; off; off >>= 1) s += __shfl_down(s, off);
    __shared__ double swm[8];
    __shared__ double smean;
    if (lane == 0) swm[wave] = s;
    __syncthreads();
    if (t == 0) {
        double m = 0.0;
        #pragma unroll
        for (int w = 0; w < 8; ++w) m += swm[w];
        smean = m / (double)B_;
    }
    __syncthreads();
    double m = smean;
    double d = (double)target[(size_t)t * OUT_ + c] - v;
    double t_s = d * d;
    double c_s = fabs(v - m);
    for (int off = 32; off; off >>= 1) {
        t_s += __shfl_down(t_s, off);
        c_s += __shfl_down(c_s, off);
    }
    __shared__ double st[8], sc[8];
    if (lane == 0) { st[wave] = t_s; sc[wave] = c_s; }
    __syncthreads();
    if (t == 0) {
        double ts = 0.0, cs = 0.0;
        #pragma unroll
        for (int w = 0; w < 8; ++w) { ts += st[w]; cs += sc[w]; }
        t_part[c] = ts;
        c_part[c] = cs;
    }
}

// dispatch 5: pdist on 256 blocks; mean/MSE/compactness on blocks 0..63
__global__ __launch_bounds__(NTHR) void pd_k(
    const double* __restrict__ yv, const float* __restrict__ target,
    const double* __restrict__ wbc, double* __restrict__ hom_part,
    double* __restrict__ t_part, double* __restrict__ c_part) {
    __shared__ double slo[NSORT], shi[NSORT];
    __shared__ double yA[OUT_], yB[OUT_];
    const int t = threadIdx.x, bid = blockIdx.x;
    slo[t] = wbc[t];
    shi[t] = wbc[NSORT + t];
    pdist_dev(yv, hom_part, bid, t, yA, yB, slo, shi);   // syncs before use
    if (bid < OUT_) mc_dev(target, yv, t_part, c_part, bid, t);
}

// dispatch 6: final reduction (1 block)
__global__ __launch_bounds__(NTHR) void fin_k(
    const double* __restrict__ hom_part, const double* __restrict__ t_part,
    const double* __restrict__ c_part, float* __restrict__ out) {
    const int t = threadIdx.x;
    double h = 0.0, tp = 0.0, cp = 0.0;
    if (t < 256)  h = hom_part[t];
    if (t < OUT_) { tp = t_part[t]; cp = c_part[t]; }
    for (int off = 32; off; off >>= 1) {
        h  += __shfl_down(h,  off);
        tp += __shfl_down(tp, off);
        cp += __shfl_down(cp, off);
    }
    __shared__ double sh[8], stp[8], scp[8];
    int wave = t >> 6, lane = t & 63;
    if (lane == 0) { sh[wave] = h; stp[wave] = tp; scp[wave] = cp; }
    __syncthreads();
    if (t == 0) {
        double hs = 0.0, ts = 0.0, cs = 0.0;
        #pragma unroll
        for (int w = 0; w < 8; ++w) { hs += sh[w]; ts += stp[w]; cs += scp[w]; }
        out[0] = (float)(ts / (double)(B_ * OUT_) + hs + 0.01 * cs);
    }
}

extern "C" void kernel_launch(void* const* d_in, const int* in_sizes, int n_in,
                              void* d_out, int out_size, void* d_ws, size_t ws_size,
                              hipStream_t stream) {
    const float* batch  = (const float*)d_in[0];
    const float* target = (const float*)d_in[1];
    const float* W1     = (const float*)d_in[2];
    const float* b1     = (const float*)d_in[3];
    const float* W2     = (const float*)d_in[4];
    const float* b2     = (const float*)d_in[5];
    const float* W3     = (const float*)d_in[6];
    const float* b3     = (const float*)d_in[7];
    const float* Wout   = (const float*)d_in[8];
    const float* bout   = (const float*)d_in[9];
    const float* deaths = (const float*)d_in[10];
    float* out = (float*)d_out;

    double* hA       = (double*)d_ws;              // 512*512
    double* hB       = hA + (size_t)B_ * H_;       // 512*512
    double* hC       = hB + (size_t)B_ * H_;       // 512*512
    double* yv       = hC + (size_t)B_ * H_;       // 512*64
    double* hom_part = yv + (size_t)B_ * OUT_;     // 256
    double* t_part   = hom_part + 256;             // 64
    double* c_part   = t_part + OUT_;              // 64
    double* wbc      = c_part + OUT_;              // 1024 doubles (lo|hi)

    g1s_k<<<dim3(257), dim3(NTHR), 0, stream>>>(batch, W1, b1, hA, deaths, wbc);
    gemm_k<true><<<dim3(256), dim3(NTHR), 0, stream>>>(hA, W2, b2, hB);
    gemm_k<true><<<dim3(256), dim3(NTHR), 0, stream>>>(hB, W3, b3, hC);
    gout_k<<<dim3(32), dim3(NTHR), 0, stream>>>(hC, Wout, bout, yv);
    pd_k<<<dim3(256), dim3(NTHR), 0, stream>>>(yv, target, wbc,
                                               hom_part, t_part, c_part);
    fin_k<<<dim3(1), dim3(NTHR), 0, stream>>>(hom_part, t_part, c_part, out);
}